// Round 17
// baseline (230.252 us; speedup 1.0000x reference)
//
#include <hip/hip_runtime.h>

#define N_FEAT 128
#define HID 16
#define NPB 128          // nodes per fine bucket (7-bit local dst)
#define KMAX 1024        // max fine buckets (K = 782 here)
#define SEGCAP 8192      // max edges per fine bucket in sort LDS
#define EPT 4            // edges per thread in bin_kernel (1024 thr, 782 blocks)
#define BATCH 16         // parallel gathers per batch in agg kernels

// ctrl region (ints): bcnt@0(1024) | bstart@1024(1056) | gcursorF@2080(1024)
#define CTRL_INTS 3584

// ================= fine histogram (dst>>7) ================================
__global__ void bhist_kernel(const int* __restrict__ dst,
                             int* __restrict__ bcnt, int E, int K) {
    __shared__ int h[KMAX];
    for (int i = threadIdx.x; i < KMAX; i += 256) h[i] = 0;
    __syncthreads();
    for (long long e = (long long)blockIdx.x * 256 + threadIdx.x; e < E;
         e += (long long)gridDim.x * 256)
        atomicAdd(&h[__builtin_nontemporal_load(&dst[e]) >> 7], 1);
    __syncthreads();
    for (int i = threadIdx.x; i < K; i += 256)
        if (h[i]) atomicAdd(&bcnt[i], h[i]);
}

// ================= scan of fine-bucket counts =============================
__global__ void bscan_kernel(const int* __restrict__ bcnt,
                             int* __restrict__ bstart,
                             int* __restrict__ gcursorF, int K, int E) {
    __shared__ int l[KMAX];
    int t = threadIdx.x;
    int v = (t < K) ? bcnt[t] : 0;
    l[t] = v;
    __syncthreads();
    for (int off = 1; off < KMAX; off <<= 1) {
        int tmp = (t >= off) ? l[t - off] : 0;
        __syncthreads();
        l[t] += tmp;
        __syncthreads();
    }
    int excl = l[t] - v;
    bstart[t]   = excl;          // == E for t >= K
    gcursorF[t] = excl;
    if (t == 0) bstart[KMAX] = E;
}

// ===== one-level binning: 1024 threads, EPT=4 (proven r14) ================
__global__ void bin_kernel(const int* __restrict__ src,
                           const int* __restrict__ dst,
                           int* __restrict__ gcursor,
                           int* __restrict__ binned, int E) {
    __shared__ int rcnt[KMAX];
    __shared__ int rbase[KMAX];
    int base = blockIdx.x * (1024 * EPT);
    if (base >= E) return;

    for (int i = threadIdx.x; i < KMAX; i += 1024) rcnt[i] = 0;
    __syncthreads();

    int myb[EPT], myoff[EPT], mypack[EPT];
#pragma unroll
    for (int q = 0; q < EPT; ++q) {
        int e = base + q * 1024 + threadIdx.x;
        myb[q] = -1;
        if (e < E) {
            int d = __builtin_nontemporal_load(&dst[e]);
            int s = __builtin_nontemporal_load(&src[e]);
            int b = d >> 7;
            myb[q]    = b;
            mypack[q] = ((d & 127) << 17) | s;
            myoff[q]  = atomicAdd(&rcnt[b], 1);
        }
    }
    __syncthreads();
    for (int i = threadIdx.x; i < KMAX; i += 1024) {
        int c = rcnt[i];
        if (c > 0) rbase[i] = atomicAdd(&gcursor[i], c);
    }
    __syncthreads();
#pragma unroll
    for (int q = 0; q < EPT; ++q)
        if (myb[q] >= 0) binned[rbase[myb[q]] + myoff[q]] = mypack[q];
}

// ===== per-fine-bucket counting sort (in place, 1024 thr) + row_start + dinv
__global__ void sort_kernel(const int* __restrict__ bstart,
                            int* __restrict__ binned,
                            int* __restrict__ row_start,
                            float* __restrict__ dinv, int n, int E) {
    __shared__ int seg[SEGCAP];
    __shared__ int cnt[NPB];
    __shared__ int excl[NPB];
    __shared__ int cur[NPB];
    int b = blockIdx.x;
    int rs = bstart[b], re = bstart[b + 1];
    int m = re - rs;
    if (m > SEGCAP) m = SEGCAP;
    int t = threadIdx.x;

    if (t < NPB) cnt[t] = 0;
    __syncthreads();

    for (int k = t; k < m; k += 1024) {
        int p = binned[rs + k];
        seg[k] = p;
        atomicAdd(&cnt[p >> 17], 1);
    }
    __syncthreads();

    if (t < NPB) excl[t] = cnt[t];
    __syncthreads();
    for (int off = 1; off < NPB; off <<= 1) {
        int v = (t < NPB && t >= off) ? excl[t - off] : 0;
        __syncthreads();
        if (t < NPB) excl[t] += v;
        __syncthreads();
    }

    int vbase = b * NPB;
    if (t < NPB) {
        int e0 = excl[t] - cnt[t];
        cur[t] = e0;
        int v = vbase + t;
        if (v < n) {
            row_start[v] = rs + e0;
            dinv[v] = rsqrtf((float)cnt[t] + 1.0f);
        }
    }
    if (b == 0 && t == 0) row_start[n] = E;
    __syncthreads();

    for (int k = t; k < m; k += 1024) {
        int p = seg[k];
        int pos = rs + atomicAdd(&cur[p >> 17], 1);
        binned[pos] = p & 0x1FFFF;                 // sorted src
    }
}

// ================= xform1: g1[v,:] = (x[v,:] @ W1) * dinv[v] ==============
__global__ void xform1_kernel(const float* __restrict__ x,
                              const float* __restrict__ W1,
                              const float* __restrict__ dinv,
                              float* __restrict__ g1, int n) {
    __shared__ float Ws[N_FEAT * HID];
    for (int i = threadIdx.x; i < N_FEAT * HID; i += blockDim.x)
        Ws[i] = W1[i];
    __syncthreads();

    int v = blockIdx.x * blockDim.x + threadIdx.x;
    if (v >= n) return;

    float acc[HID];
#pragma unroll
    for (int j = 0; j < HID; ++j) acc[j] = 0.0f;

    const float4* xr = (const float4*)(x + (size_t)v * N_FEAT);
#pragma unroll
    for (int k4 = 0; k4 < N_FEAT / 4; ++k4) {
        float4 xv = xr[k4];
        int k = k4 * 4;
#pragma unroll
        for (int j = 0; j < HID; ++j) {
            acc[j] += xv.x * Ws[(k + 0) * HID + j]
                    + xv.y * Ws[(k + 1) * HID + j]
                    + xv.z * Ws[(k + 2) * HID + j]
                    + xv.w * Ws[(k + 3) * HID + j];
        }
    }
    float dv = dinv[v];
    float4* outp = (float4*)(g1 + (size_t)v * HID);
#pragma unroll
    for (int q = 0; q < HID / 4; ++q) {
        float4 o;
        o.x = acc[q * 4 + 0] * dv;
        o.y = acc[q * 4 + 1] * dv;
        o.z = acc[q * 4 + 2] * dv;
        o.w = acc[q * 4 + 3] * dv;
        outp[q] = o;
    }
}

// ===== layer-1 aggregation + FUSED finalize/relu/W2 (register-only epi) ===
__global__ __launch_bounds__(256) void agg1_fused_kernel(
        const int* __restrict__ row_start,
        const int* __restrict__ slots,
        const float4* __restrict__ g,      // g1, 4 x float4 per node
        const float* __restrict__ dinv,
        const float* __restrict__ b1,
        const float* __restrict__ W2,
        float4* __restrict__ g2, int n) {
    __shared__ float W2s[HID * HID];
    W2s[threadIdx.x] = W2[threadIdx.x];    // blockDim == 256 == HID*HID
    __syncthreads();

    int v = blockIdx.x * 64 + (threadIdx.x >> 2);
    int h = threadIdx.x & 3;
    if (v >= n) return;

    int rs = row_start[v], re = row_start[v + 1];
    float4 s0 = {0.f,0.f,0.f,0.f}, s1 = s0, s2 = s0, s3 = s0;

    for (int k = rs; k < re; k += BATCH) {
        int e[BATCH];
#pragma unroll
        for (int u = 0; u < BATCH; ++u)
            e[u] = __builtin_nontemporal_load(&slots[min(k + u, re - 1)]);
        float4 t[BATCH];
#pragma unroll
        for (int u = 0; u < BATCH; ++u)
            t[u] = g[(size_t)e[u] * 4 + h];
#pragma unroll
        for (int u = 0; u < BATCH; ++u) {
            if (k + u < re) {
                if ((u & 3) == 0) { s0.x += t[u].x; s0.y += t[u].y; s0.z += t[u].z; s0.w += t[u].w; }
                else if ((u & 3) == 1) { s1.x += t[u].x; s1.y += t[u].y; s1.z += t[u].z; s1.w += t[u].w; }
                else if ((u & 3) == 2) { s2.x += t[u].x; s2.y += t[u].y; s2.z += t[u].z; s2.w += t[u].w; }
                else { s3.x += t[u].x; s3.y += t[u].y; s3.z += t[u].z; s3.w += t[u].w; }
            }
        }
    }
    float4 r;
    r.x = (s0.x + s1.x) + (s2.x + s3.x);
    r.y = (s0.y + s1.y) + (s2.y + s3.y);
    r.z = (s0.z + s1.z) + (s2.z + s3.z);
    r.w = (s0.w + s1.w) + (s2.w + s3.w);

    // ---- fused epilogue (registers only) ----
    float dv = dinv[v];
    float4 self = g[(size_t)v * 4 + h];
    float4 bb = ((const float4*)b1)[h];
    float t0 = fmaxf(dv * (r.x + self.x) + bb.x, 0.0f);
    float t1 = fmaxf(dv * (r.y + self.y) + bb.y, 0.0f);
    float t2 = fmaxf(dv * (r.z + self.z) + bb.z, 0.0f);
    float t3 = fmaxf(dv * (r.w + self.w) + bb.w, 0.0f);

    int j0 = h * 4;
    float4 p0, p1, p2, p3;
    {
        const float4* w0 = (const float4*)&W2s[(j0 + 0) * HID + 0];
        const float4* w1 = (const float4*)&W2s[(j0 + 1) * HID + 0];
        const float4* w2 = (const float4*)&W2s[(j0 + 2) * HID + 0];
        const float4* w3 = (const float4*)&W2s[(j0 + 3) * HID + 0];
#define PART(dstv, q)                                                     \
        {                                                                 \
            float4 a0 = w0[q], a1 = w1[q], a2 = w2[q], a3 = w3[q];        \
            dstv.x = t0 * a0.x + t1 * a1.x + t2 * a2.x + t3 * a3.x;       \
            dstv.y = t0 * a0.y + t1 * a1.y + t2 * a2.y + t3 * a3.y;       \
            dstv.z = t0 * a0.z + t1 * a1.z + t2 * a2.z + t3 * a3.z;       \
            dstv.w = t0 * a0.w + t1 * a1.w + t2 * a2.w + t3 * a3.w;       \
        }
        PART(p0, 0) PART(p1, 1) PART(p2, 2) PART(p3, 3)
#undef PART
    }
#pragma unroll
    for (int m = 1; m < 4; m <<= 1) {
        p0.x += __shfl_xor(p0.x, m, 4); p0.y += __shfl_xor(p0.y, m, 4);
        p0.z += __shfl_xor(p0.z, m, 4); p0.w += __shfl_xor(p0.w, m, 4);
        p1.x += __shfl_xor(p1.x, m, 4); p1.y += __shfl_xor(p1.y, m, 4);
        p1.z += __shfl_xor(p1.z, m, 4); p1.w += __shfl_xor(p1.w, m, 4);
        p2.x += __shfl_xor(p2.x, m, 4); p2.y += __shfl_xor(p2.y, m, 4);
        p2.z += __shfl_xor(p2.z, m, 4); p2.w += __shfl_xor(p2.w, m, 4);
        p3.x += __shfl_xor(p3.x, m, 4); p3.y += __shfl_xor(p3.y, m, 4);
        p3.z += __shfl_xor(p3.z, m, 4); p3.w += __shfl_xor(p3.w, m, 4);
    }
    float4 sel = p0;
    if (h == 1) sel = p1;
    if (h == 2) sel = p2;
    if (h == 3) sel = p3;

    float4 o;
    o.x = sel.x * dv;
    o.y = sel.y * dv;
    o.z = sel.z * dv;
    o.w = sel.w * dv;
    g2[(size_t)v * 4 + h] = o;
}

// ===== layer-2 aggregation + finalize + bias ==============================
__global__ __launch_bounds__(256) void agg_fin_kernel(
        const int* __restrict__ row_start,
        const int* __restrict__ slots,
        const float4* __restrict__ g,      // g2, 4 x float4 per node
        const float* __restrict__ dinv,
        const float* __restrict__ b2,
        float4* __restrict__ out, int n) {
    int v = blockIdx.x * 64 + (threadIdx.x >> 2);
    int h = threadIdx.x & 3;
    if (v >= n) return;

    int rs = row_start[v], re = row_start[v + 1];
    float4 s0 = {0.f,0.f,0.f,0.f}, s1 = s0, s2 = s0, s3 = s0;

    for (int k = rs; k < re; k += BATCH) {
        int e[BATCH];
#pragma unroll
        for (int u = 0; u < BATCH; ++u)
            e[u] = __builtin_nontemporal_load(&slots[min(k + u, re - 1)]);
        float4 t[BATCH];
#pragma unroll
        for (int u = 0; u < BATCH; ++u)
            t[u] = g[(size_t)e[u] * 4 + h];
#pragma unroll
        for (int u = 0; u < BATCH; ++u) {
            if (k + u < re) {
                if ((u & 3) == 0) { s0.x += t[u].x; s0.y += t[u].y; s0.z += t[u].z; s0.w += t[u].w; }
                else if ((u & 3) == 1) { s1.x += t[u].x; s1.y += t[u].y; s1.z += t[u].z; s1.w += t[u].w; }
                else if ((u & 3) == 2) { s2.x += t[u].x; s2.y += t[u].y; s2.z += t[u].z; s2.w += t[u].w; }
                else { s3.x += t[u].x; s3.y += t[u].y; s3.z += t[u].z; s3.w += t[u].w; }
            }
        }
    }
    float4 acc;
    acc.x = (s0.x + s1.x) + (s2.x + s3.x);
    acc.y = (s0.y + s1.y) + (s2.y + s3.y);
    acc.z = (s0.z + s1.z) + (s2.z + s3.z);
    acc.w = (s0.w + s1.w) + (s2.w + s3.w);

    float dv = dinv[v];
    float4 self = g[(size_t)v * 4 + h];
    float4 bb = ((const float4*)b2)[h];
    float4 o;
    o.x = dv * (acc.x + self.x) + bb.x;
    o.y = dv * (acc.y + self.y) + bb.y;
    o.z = dv * (acc.z + self.z) + bb.z;
    o.w = dv * (acc.w + self.w) + bb.w;
    out[(size_t)v * 4 + h] = o;
}

// ========================= fallback (atomic) path ==========================
__global__ void deg_kernel(const int* __restrict__ dst,
                           float* __restrict__ deg, int E) {
    int e = blockIdx.x * blockDim.x + threadIdx.x;
    if (e < E) atomicAdd(&deg[dst[e]], 1.0f);
}

__global__ void dinv_kernel(float* __restrict__ deg, int n) {
    int v = blockIdx.x * blockDim.x + threadIdx.x;
    if (v < n) deg[v] = rsqrtf(deg[v] + 1.0f);
}

__global__ void agg_kernel(const int* __restrict__ src,
                           const int* __restrict__ dst,
                           const float* __restrict__ g,
                           float* __restrict__ acc, long long total) {
    long long i = (long long)blockIdx.x * blockDim.x + threadIdx.x;
    if (i >= total) return;
    int e = (int)(i >> 4);
    int j = (int)(i & 15);
    atomicAdd(&acc[(size_t)dst[e] * HID + j], g[(size_t)src[e] * HID + j]);
}

__global__ void fin1_xform2_nolds_kernel(float* __restrict__ a1,
                                         const float* __restrict__ g1,
                                         const float* __restrict__ dinv,
                                         const float* __restrict__ b1,
                                         const float* __restrict__ W2,
                                         int n) {
    int v = blockIdx.x * blockDim.x + threadIdx.x;
    if (v >= n) return;
    float dv = dinv[v];
    const float4* a4 = (const float4*)(a1 + (size_t)v * HID);
    const float4* s4 = (const float4*)(g1 + (size_t)v * HID);
    float t[HID];
#pragma unroll
    for (int q = 0; q < HID / 4; ++q) {
        float4 av = a4[q];
        float4 sv = s4[q];
        t[q * 4 + 0] = fmaxf(dv * (av.x + sv.x) + b1[q * 4 + 0], 0.0f);
        t[q * 4 + 1] = fmaxf(dv * (av.y + sv.y) + b1[q * 4 + 1], 0.0f);
        t[q * 4 + 2] = fmaxf(dv * (av.z + sv.z) + b1[q * 4 + 2], 0.0f);
        t[q * 4 + 3] = fmaxf(dv * (av.w + sv.w) + b1[q * 4 + 3], 0.0f);
    }
    float4* outp = (float4*)(a1 + (size_t)v * HID);
#pragma unroll
    for (int q = 0; q < HID / 4; ++q) {
        float4 o;
        float h[4];
#pragma unroll
        for (int r = 0; r < 4; ++r) {
            int j2 = q * 4 + r;
            float acc = 0.0f;
#pragma unroll
            for (int j = 0; j < HID; ++j) acc += t[j] * W2[j * HID + j2];
            h[r] = acc * dv;
        }
        o.x = h[0]; o.y = h[1]; o.z = h[2]; o.w = h[3];
        outp[q] = o;
    }
}

__global__ void fin2_kernel(float* __restrict__ out,
                            const float* __restrict__ g2,
                            const float* __restrict__ dinv,
                            const float* __restrict__ b2, int n) {
    int v = blockIdx.x * blockDim.x + threadIdx.x;
    if (v >= n) return;
    float dv = dinv[v];
    float4* o4 = (float4*)(out + (size_t)v * HID);
    const float4* g4 = (const float4*)(g2 + (size_t)v * HID);
#pragma unroll
    for (int q = 0; q < HID / 4; ++q) {
        float4 ov = o4[q];
        float4 gv = g4[q];
        float4 r;
        r.x = dv * (ov.x + gv.x) + b2[q * 4 + 0];
        r.y = dv * (ov.y + gv.y) + b2[q * 4 + 1];
        r.z = dv * (ov.z + gv.z) + b2[q * 4 + 2];
        r.w = dv * (ov.w + gv.w) + b2[q * 4 + 3];
        o4[q] = r;
    }
}

// ===========================================================================
extern "C" void kernel_launch(void* const* d_in, const int* in_sizes, int n_in,
                              void* d_out, int out_size, void* d_ws, size_t ws_size,
                              hipStream_t stream) {
    const float* x  = (const float*)d_in[0];
    const int*   ei = (const int*)d_in[1];     // int32 (JAX x64 disabled)
    const float* W1 = (const float*)d_in[2];
    const float* b1 = (const float*)d_in[3];
    const float* W2 = (const float*)d_in[4];
    const float* b2 = (const float*)d_in[5];
    float* out = (float*)d_out;

    const int n = in_sizes[0] / N_FEAT;         // 100000
    const int E = in_sizes[1] / 2;              // 3200000
    const int* src = ei;
    const int* dst = ei + E;

    const int B = 256;
    size_t nal = ((size_t)n + 255) & ~(size_t)255;
    const int K = (n + NPB - 1) / NPB;          // 782 fine buckets

    // ws: binned(E) | ctrl | row_start(nal+64) | dinv(nal) | g1(16nal) | g2(16nal)
    size_t need = ((size_t)E + CTRL_INTS + 34 * nal + 64) * sizeof(int);

    if (ws_size >= need && K <= KMAX) {
        int*   binned    = (int*)d_ws;                   // E
        int*   ctrl      = binned + E;                   // CTRL_INTS
        int*   bcnt      = ctrl;                         // 1024
        int*   bstart    = ctrl + 1024;                  // 1056
        int*   gcursorF  = ctrl + 2080;                  // 1024
        int*   row_start = ctrl + CTRL_INTS;             // nal + 64
        float* dinv      = (float*)(row_start + nal + 64);
        float* g1        = dinv + nal;                   // 16*nal (64B rows)
        float* g2        = g1 + 16 * nal;                // 16*nal

        hipMemsetAsync(bcnt, 0, 1024 * sizeof(int), stream);

        bhist_kernel<<<512, 256, 0, stream>>>(dst, bcnt, E, K);
        bscan_kernel<<<1, KMAX, 0, stream>>>(bcnt, bstart, gcursorF, K, E);

        int nblk = (E + 1024 * EPT - 1) / (1024 * EPT);  // 782 blocks
        bin_kernel<<<nblk, 1024, 0, stream>>>(src, dst, gcursorF, binned, E);

        sort_kernel<<<K, 1024, 0, stream>>>(bstart, binned, row_start, dinv, n, E);

        xform1_kernel<<<(n + B - 1) / B, B, 0, stream>>>(x, W1, dinv, g1, n);

        int nb64 = (n + 63) / 64;
        agg1_fused_kernel<<<nb64, 256, 0, stream>>>(row_start, binned,
                                                    (const float4*)g1, dinv,
                                                    b1, W2, (float4*)g2, n);
        agg_fin_kernel<<<nb64, 256, 0, stream>>>(row_start, binned,
                                                 (const float4*)g2, dinv, b2,
                                                 (float4*)out, n);
    } else {
        // fallback: proven atomic path
        float* w   = (float*)d_ws;
        float* deg = w;                  // nal  (becomes dinv)
        float* a1  = w + nal;            // 16*nal (becomes g2)
        float* g1  = a1 + 16 * nal;      // 16*nal

        hipMemsetAsync(d_ws, 0, (nal * 17) * sizeof(float), stream);
        hipMemsetAsync(d_out, 0, (size_t)out_size * sizeof(float), stream);

        deg_kernel<<<(E + B - 1) / B, B, 0, stream>>>(dst, deg, E);
        dinv_kernel<<<(n + B - 1) / B, B, 0, stream>>>(deg, n);
        xform1_kernel<<<(n + B - 1) / B, B, 0, stream>>>(x, W1, deg, g1, n);
        long long total = (long long)E * HID;
        agg_kernel<<<(int)((total + B - 1) / B), B, 0, stream>>>(src, dst, g1, a1, total);
        fin1_xform2_nolds_kernel<<<(n + B - 1) / B, B, 0, stream>>>(a1, g1, deg, b1, W2, n);
        agg_kernel<<<(int)((total + B - 1) / B), B, 0, stream>>>(src, dst, a1, out, total);
        fin2_kernel<<<(n + B - 1) / B, B, 0, stream>>>(out, a1, deg, b2, n);
    }
}

// Round 18
// 181.627 us; speedup vs baseline: 1.2677x; 1.2677x over previous
//
#include <hip/hip_runtime.h>

#define N_FEAT 128
#define HID 16
#define NPB 128          // nodes per fine bucket (7-bit local dst)
#define KMAX 1024        // max fine buckets (K = 782 here)
#define SEGCAP 8192      // max edges per fine bucket in sort LDS
#define EPT 4            // edges per thread in bin_kernel (1024 thr, 782 blocks)
#define BATCH 16         // parallel gathers per batch in agg kernels

// ctrl region (ints): bcnt@0(1024) | bstart@1024(1056) | gcursorF@2080(1024)
#define CTRL_INTS 3584

// ================= fine histogram (dst>>7) ================================
__global__ void bhist_kernel(const int* __restrict__ dst,
                             int* __restrict__ bcnt, int E, int K) {
    __shared__ int h[KMAX];
    for (int i = threadIdx.x; i < KMAX; i += 256) h[i] = 0;
    __syncthreads();
    for (long long e = (long long)blockIdx.x * 256 + threadIdx.x; e < E;
         e += (long long)gridDim.x * 256)
        atomicAdd(&h[dst[e] >> 7], 1);
    __syncthreads();
    for (int i = threadIdx.x; i < K; i += 256)
        if (h[i]) atomicAdd(&bcnt[i], h[i]);
}

// ================= scan of fine-bucket counts =============================
__global__ void bscan_kernel(const int* __restrict__ bcnt,
                             int* __restrict__ bstart,
                             int* __restrict__ gcursorF, int K, int E) {
    __shared__ int l[KMAX];
    int t = threadIdx.x;
    int v = (t < K) ? bcnt[t] : 0;
    l[t] = v;
    __syncthreads();
    for (int off = 1; off < KMAX; off <<= 1) {
        int tmp = (t >= off) ? l[t - off] : 0;
        __syncthreads();
        l[t] += tmp;
        __syncthreads();
    }
    int excl = l[t] - v;
    bstart[t]   = excl;          // == E for t >= K
    gcursorF[t] = excl;
    if (t == 0) bstart[KMAX] = E;
}

// ===== one-level binning: 1024 threads, EPT=4 (proven r14) ================
__global__ void bin_kernel(const int* __restrict__ src,
                           const int* __restrict__ dst,
                           int* __restrict__ gcursor,
                           int* __restrict__ binned, int E) {
    __shared__ int rcnt[KMAX];
    __shared__ int rbase[KMAX];
    int base = blockIdx.x * (1024 * EPT);
    if (base >= E) return;

    for (int i = threadIdx.x; i < KMAX; i += 1024) rcnt[i] = 0;
    __syncthreads();

    int myb[EPT], myoff[EPT], mypack[EPT];
#pragma unroll
    for (int q = 0; q < EPT; ++q) {
        int e = base + q * 1024 + threadIdx.x;
        myb[q] = -1;
        if (e < E) {
            int d = dst[e], s = src[e];
            int b = d >> 7;
            myb[q]    = b;
            mypack[q] = ((d & 127) << 17) | s;
            myoff[q]  = atomicAdd(&rcnt[b], 1);
        }
    }
    __syncthreads();
    for (int i = threadIdx.x; i < KMAX; i += 1024) {
        int c = rcnt[i];
        if (c > 0) rbase[i] = atomicAdd(&gcursor[i], c);
    }
    __syncthreads();
#pragma unroll
    for (int q = 0; q < EPT; ++q)
        if (myb[q] >= 0) binned[rbase[myb[q]] + myoff[q]] = mypack[q];
}

// ===== per-fine-bucket counting sort (in place, 1024 thr) + row_start + dinv
__global__ void sort_kernel(const int* __restrict__ bstart,
                            int* __restrict__ binned,
                            int* __restrict__ row_start,
                            float* __restrict__ dinv, int n, int E) {
    __shared__ int seg[SEGCAP];
    __shared__ int cnt[NPB];
    __shared__ int excl[NPB];
    __shared__ int cur[NPB];
    int b = blockIdx.x;
    int rs = bstart[b], re = bstart[b + 1];
    int m = re - rs;
    if (m > SEGCAP) m = SEGCAP;
    int t = threadIdx.x;

    if (t < NPB) cnt[t] = 0;
    __syncthreads();

    for (int k = t; k < m; k += 1024) {
        int p = binned[rs + k];
        seg[k] = p;
        atomicAdd(&cnt[p >> 17], 1);
    }
    __syncthreads();

    if (t < NPB) excl[t] = cnt[t];
    __syncthreads();
    for (int off = 1; off < NPB; off <<= 1) {
        int v = (t < NPB && t >= off) ? excl[t - off] : 0;
        __syncthreads();
        if (t < NPB) excl[t] += v;
        __syncthreads();
    }

    int vbase = b * NPB;
    if (t < NPB) {
        int e0 = excl[t] - cnt[t];
        cur[t] = e0;
        int v = vbase + t;
        if (v < n) {
            row_start[v] = rs + e0;
            dinv[v] = rsqrtf((float)cnt[t] + 1.0f);
        }
    }
    if (b == 0 && t == 0) row_start[n] = E;
    __syncthreads();

    for (int k = t; k < m; k += 1024) {
        int p = seg[k];
        int pos = rs + atomicAdd(&cur[p >> 17], 1);
        binned[pos] = p & 0x1FFFF;                 // sorted src
    }
}

// ================= xform1: g1[v,:] = (x[v,:] @ W1) * dinv[v] ==============
__global__ void xform1_kernel(const float* __restrict__ x,
                              const float* __restrict__ W1,
                              const float* __restrict__ dinv,
                              float* __restrict__ g1, int n) {
    __shared__ float Ws[N_FEAT * HID];
    for (int i = threadIdx.x; i < N_FEAT * HID; i += blockDim.x)
        Ws[i] = W1[i];
    __syncthreads();

    int v = blockIdx.x * blockDim.x + threadIdx.x;
    if (v >= n) return;

    float acc[HID];
#pragma unroll
    for (int j = 0; j < HID; ++j) acc[j] = 0.0f;

    const float4* xr = (const float4*)(x + (size_t)v * N_FEAT);
#pragma unroll
    for (int k4 = 0; k4 < N_FEAT / 4; ++k4) {
        float4 xv = xr[k4];
        int k = k4 * 4;
#pragma unroll
        for (int j = 0; j < HID; ++j) {
            acc[j] += xv.x * Ws[(k + 0) * HID + j]
                    + xv.y * Ws[(k + 1) * HID + j]
                    + xv.z * Ws[(k + 2) * HID + j]
                    + xv.w * Ws[(k + 3) * HID + j];
        }
    }
    float dv = dinv[v];
    float4* outp = (float4*)(g1 + (size_t)v * HID);
#pragma unroll
    for (int q = 0; q < HID / 4; ++q) {
        float4 o;
        o.x = acc[q * 4 + 0] * dv;
        o.y = acc[q * 4 + 1] * dv;
        o.z = acc[q * 4 + 2] * dv;
        o.w = acc[q * 4 + 3] * dv;
        outp[q] = o;
    }
}

// ===== layer-1 aggregation + FUSED finalize/relu/W2 (register-only epi) ===
__global__ __launch_bounds__(256) void agg1_fused_kernel(
        const int* __restrict__ row_start,
        const int* __restrict__ slots,
        const float4* __restrict__ g,      // g1, 4 x float4 per node
        const float* __restrict__ dinv,
        const float* __restrict__ b1,
        const float* __restrict__ W2,
        float4* __restrict__ g2, int n) {
    __shared__ float W2s[HID * HID];
    W2s[threadIdx.x] = W2[threadIdx.x];    // blockDim == 256 == HID*HID
    __syncthreads();

    int v = blockIdx.x * 64 + (threadIdx.x >> 2);
    int h = threadIdx.x & 3;
    if (v >= n) return;

    int rs = row_start[v], re = row_start[v + 1];
    float4 s0 = {0.f,0.f,0.f,0.f}, s1 = s0, s2 = s0, s3 = s0;

    for (int k = rs; k < re; k += BATCH) {
        int e[BATCH];
#pragma unroll
        for (int u = 0; u < BATCH; ++u)
            e[u] = slots[min(k + u, re - 1)];
        float4 t[BATCH];
#pragma unroll
        for (int u = 0; u < BATCH; ++u)
            t[u] = g[(size_t)e[u] * 4 + h];
#pragma unroll
        for (int u = 0; u < BATCH; ++u) {
            if (k + u < re) {
                if ((u & 3) == 0) { s0.x += t[u].x; s0.y += t[u].y; s0.z += t[u].z; s0.w += t[u].w; }
                else if ((u & 3) == 1) { s1.x += t[u].x; s1.y += t[u].y; s1.z += t[u].z; s1.w += t[u].w; }
                else if ((u & 3) == 2) { s2.x += t[u].x; s2.y += t[u].y; s2.z += t[u].z; s2.w += t[u].w; }
                else { s3.x += t[u].x; s3.y += t[u].y; s3.z += t[u].z; s3.w += t[u].w; }
            }
        }
    }
    float4 r;
    r.x = (s0.x + s1.x) + (s2.x + s3.x);
    r.y = (s0.y + s1.y) + (s2.y + s3.y);
    r.z = (s0.z + s1.z) + (s2.z + s3.z);
    r.w = (s0.w + s1.w) + (s2.w + s3.w);

    // ---- fused epilogue (registers only) ----
    float dv = dinv[v];
    float4 self = g[(size_t)v * 4 + h];
    float4 bb = ((const float4*)b1)[h];
    float t0 = fmaxf(dv * (r.x + self.x) + bb.x, 0.0f);
    float t1 = fmaxf(dv * (r.y + self.y) + bb.y, 0.0f);
    float t2 = fmaxf(dv * (r.z + self.z) + bb.z, 0.0f);
    float t3 = fmaxf(dv * (r.w + self.w) + bb.w, 0.0f);

    int j0 = h * 4;
    float4 p0, p1, p2, p3;
    {
        const float4* w0 = (const float4*)&W2s[(j0 + 0) * HID + 0];
        const float4* w1 = (const float4*)&W2s[(j0 + 1) * HID + 0];
        const float4* w2 = (const float4*)&W2s[(j0 + 2) * HID + 0];
        const float4* w3 = (const float4*)&W2s[(j0 + 3) * HID + 0];
#define PART(dstv, q)                                                     \
        {                                                                 \
            float4 a0 = w0[q], a1 = w1[q], a2 = w2[q], a3 = w3[q];        \
            dstv.x = t0 * a0.x + t1 * a1.x + t2 * a2.x + t3 * a3.x;       \
            dstv.y = t0 * a0.y + t1 * a1.y + t2 * a2.y + t3 * a3.y;       \
            dstv.z = t0 * a0.z + t1 * a1.z + t2 * a2.z + t3 * a3.z;       \
            dstv.w = t0 * a0.w + t1 * a1.w + t2 * a2.w + t3 * a3.w;       \
        }
        PART(p0, 0) PART(p1, 1) PART(p2, 2) PART(p3, 3)
#undef PART
    }
#pragma unroll
    for (int m = 1; m < 4; m <<= 1) {
        p0.x += __shfl_xor(p0.x, m, 4); p0.y += __shfl_xor(p0.y, m, 4);
        p0.z += __shfl_xor(p0.z, m, 4); p0.w += __shfl_xor(p0.w, m, 4);
        p1.x += __shfl_xor(p1.x, m, 4); p1.y += __shfl_xor(p1.y, m, 4);
        p1.z += __shfl_xor(p1.z, m, 4); p1.w += __shfl_xor(p1.w, m, 4);
        p2.x += __shfl_xor(p2.x, m, 4); p2.y += __shfl_xor(p2.y, m, 4);
        p2.z += __shfl_xor(p2.z, m, 4); p2.w += __shfl_xor(p2.w, m, 4);
        p3.x += __shfl_xor(p3.x, m, 4); p3.y += __shfl_xor(p3.y, m, 4);
        p3.z += __shfl_xor(p3.z, m, 4); p3.w += __shfl_xor(p3.w, m, 4);
    }
    float4 sel = p0;
    if (h == 1) sel = p1;
    if (h == 2) sel = p2;
    if (h == 3) sel = p3;

    float4 o;
    o.x = sel.x * dv;
    o.y = sel.y * dv;
    o.z = sel.z * dv;
    o.w = sel.w * dv;
    g2[(size_t)v * 4 + h] = o;
}

// ===== layer-2 aggregation + finalize + bias ==============================
__global__ __launch_bounds__(256) void agg_fin_kernel(
        const int* __restrict__ row_start,
        const int* __restrict__ slots,
        const float4* __restrict__ g,      // g2, 4 x float4 per node
        const float* __restrict__ dinv,
        const float* __restrict__ b2,
        float4* __restrict__ out, int n) {
    int v = blockIdx.x * 64 + (threadIdx.x >> 2);
    int h = threadIdx.x & 3;
    if (v >= n) return;

    int rs = row_start[v], re = row_start[v + 1];
    float4 s0 = {0.f,0.f,0.f,0.f}, s1 = s0, s2 = s0, s3 = s0;

    for (int k = rs; k < re; k += BATCH) {
        int e[BATCH];
#pragma unroll
        for (int u = 0; u < BATCH; ++u)
            e[u] = slots[min(k + u, re - 1)];
        float4 t[BATCH];
#pragma unroll
        for (int u = 0; u < BATCH; ++u)
            t[u] = g[(size_t)e[u] * 4 + h];
#pragma unroll
        for (int u = 0; u < BATCH; ++u) {
            if (k + u < re) {
                if ((u & 3) == 0) { s0.x += t[u].x; s0.y += t[u].y; s0.z += t[u].z; s0.w += t[u].w; }
                else if ((u & 3) == 1) { s1.x += t[u].x; s1.y += t[u].y; s1.z += t[u].z; s1.w += t[u].w; }
                else if ((u & 3) == 2) { s2.x += t[u].x; s2.y += t[u].y; s2.z += t[u].z; s2.w += t[u].w; }
                else { s3.x += t[u].x; s3.y += t[u].y; s3.z += t[u].z; s3.w += t[u].w; }
            }
        }
    }
    float4 acc;
    acc.x = (s0.x + s1.x) + (s2.x + s3.x);
    acc.y = (s0.y + s1.y) + (s2.y + s3.y);
    acc.z = (s0.z + s1.z) + (s2.z + s3.z);
    acc.w = (s0.w + s1.w) + (s2.w + s3.w);

    float dv = dinv[v];
    float4 self = g[(size_t)v * 4 + h];
    float4 bb = ((const float4*)b2)[h];
    float4 o;
    o.x = dv * (acc.x + self.x) + bb.x;
    o.y = dv * (acc.y + self.y) + bb.y;
    o.z = dv * (acc.z + self.z) + bb.z;
    o.w = dv * (acc.w + self.w) + bb.w;
    out[(size_t)v * 4 + h] = o;
}

// ========================= fallback (atomic) path ==========================
__global__ void deg_kernel(const int* __restrict__ dst,
                           float* __restrict__ deg, int E) {
    int e = blockIdx.x * blockDim.x + threadIdx.x;
    if (e < E) atomicAdd(&deg[dst[e]], 1.0f);
}

__global__ void dinv_kernel(float* __restrict__ deg, int n) {
    int v = blockIdx.x * blockDim.x + threadIdx.x;
    if (v < n) deg[v] = rsqrtf(deg[v] + 1.0f);
}

__global__ void agg_kernel(const int* __restrict__ src,
                           const int* __restrict__ dst,
                           const float* __restrict__ g,
                           float* __restrict__ acc, long long total) {
    long long i = (long long)blockIdx.x * blockDim.x + threadIdx.x;
    if (i >= total) return;
    int e = (int)(i >> 4);
    int j = (int)(i & 15);
    atomicAdd(&acc[(size_t)dst[e] * HID + j], g[(size_t)src[e] * HID + j]);
}

__global__ void fin1_xform2_nolds_kernel(float* __restrict__ a1,
                                         const float* __restrict__ g1,
                                         const float* __restrict__ dinv,
                                         const float* __restrict__ b1,
                                         const float* __restrict__ W2,
                                         int n) {
    int v = blockIdx.x * blockDim.x + threadIdx.x;
    if (v >= n) return;
    float dv = dinv[v];
    const float4* a4 = (const float4*)(a1 + (size_t)v * HID);
    const float4* s4 = (const float4*)(g1 + (size_t)v * HID);
    float t[HID];
#pragma unroll
    for (int q = 0; q < HID / 4; ++q) {
        float4 av = a4[q];
        float4 sv = s4[q];
        t[q * 4 + 0] = fmaxf(dv * (av.x + sv.x) + b1[q * 4 + 0], 0.0f);
        t[q * 4 + 1] = fmaxf(dv * (av.y + sv.y) + b1[q * 4 + 1], 0.0f);
        t[q * 4 + 2] = fmaxf(dv * (av.z + sv.z) + b1[q * 4 + 2], 0.0f);
        t[q * 4 + 3] = fmaxf(dv * (av.w + sv.w) + b1[q * 4 + 3], 0.0f);
    }
    float4* outp = (float4*)(a1 + (size_t)v * HID);
#pragma unroll
    for (int q = 0; q < HID / 4; ++q) {
        float4 o;
        float h[4];
#pragma unroll
        for (int r = 0; r < 4; ++r) {
            int j2 = q * 4 + r;
            float acc = 0.0f;
#pragma unroll
            for (int j = 0; j < HID; ++j) acc += t[j] * W2[j * HID + j2];
            h[r] = acc * dv;
        }
        o.x = h[0]; o.y = h[1]; o.z = h[2]; o.w = h[3];
        outp[q] = o;
    }
}

__global__ void fin2_kernel(float* __restrict__ out,
                            const float* __restrict__ g2,
                            const float* __restrict__ dinv,
                            const float* __restrict__ b2, int n) {
    int v = blockIdx.x * blockDim.x + threadIdx.x;
    if (v >= n) return;
    float dv = dinv[v];
    float4* o4 = (float4*)(out + (size_t)v * HID);
    const float4* g4 = (const float4*)(g2 + (size_t)v * HID);
#pragma unroll
    for (int q = 0; q < HID / 4; ++q) {
        float4 ov = o4[q];
        float4 gv = g4[q];
        float4 r;
        r.x = dv * (ov.x + gv.x) + b2[q * 4 + 0];
        r.y = dv * (ov.y + gv.y) + b2[q * 4 + 1];
        r.z = dv * (ov.z + gv.z) + b2[q * 4 + 2];
        r.w = dv * (ov.w + gv.w) + b2[q * 4 + 3];
        o4[q] = r;
    }
}

// ===========================================================================
extern "C" void kernel_launch(void* const* d_in, const int* in_sizes, int n_in,
                              void* d_out, int out_size, void* d_ws, size_t ws_size,
                              hipStream_t stream) {
    const float* x  = (const float*)d_in[0];
    const int*   ei = (const int*)d_in[1];     // int32 (JAX x64 disabled)
    const float* W1 = (const float*)d_in[2];
    const float* b1 = (const float*)d_in[3];
    const float* W2 = (const float*)d_in[4];
    const float* b2 = (const float*)d_in[5];
    float* out = (float*)d_out;

    const int n = in_sizes[0] / N_FEAT;         // 100000
    const int E = in_sizes[1] / 2;              // 3200000
    const int* src = ei;
    const int* dst = ei + E;

    const int B = 256;
    size_t nal = ((size_t)n + 255) & ~(size_t)255;
    const int K = (n + NPB - 1) / NPB;          // 782 fine buckets

    // ws: binned(E) | ctrl | row_start(nal+64) | dinv(nal) | g1(16nal) | g2(16nal)
    size_t need = ((size_t)E + CTRL_INTS + 34 * nal + 64) * sizeof(int);

    if (ws_size >= need && K <= KMAX) {
        int*   binned    = (int*)d_ws;                   // E
        int*   ctrl      = binned + E;                   // CTRL_INTS
        int*   bcnt      = ctrl;                         // 1024
        int*   bstart    = ctrl + 1024;                  // 1056
        int*   gcursorF  = ctrl + 2080;                  // 1024
        int*   row_start = ctrl + CTRL_INTS;             // nal + 64
        float* dinv      = (float*)(row_start + nal + 64);
        float* g1        = dinv + nal;                   // 16*nal (64B rows)
        float* g2        = g1 + 16 * nal;                // 16*nal

        hipMemsetAsync(bcnt, 0, 1024 * sizeof(int), stream);

        bhist_kernel<<<512, 256, 0, stream>>>(dst, bcnt, E, K);
        bscan_kernel<<<1, KMAX, 0, stream>>>(bcnt, bstart, gcursorF, K, E);

        int nblk = (E + 1024 * EPT - 1) / (1024 * EPT);  // 782 blocks
        bin_kernel<<<nblk, 1024, 0, stream>>>(src, dst, gcursorF, binned, E);

        sort_kernel<<<K, 1024, 0, stream>>>(bstart, binned, row_start, dinv, n, E);

        xform1_kernel<<<(n + B - 1) / B, B, 0, stream>>>(x, W1, dinv, g1, n);

        int nb64 = (n + 63) / 64;
        agg1_fused_kernel<<<nb64, 256, 0, stream>>>(row_start, binned,
                                                    (const float4*)g1, dinv,
                                                    b1, W2, (float4*)g2, n);
        agg_fin_kernel<<<nb64, 256, 0, stream>>>(row_start, binned,
                                                 (const float4*)g2, dinv, b2,
                                                 (float4*)out, n);
    } else {
        // fallback: proven atomic path
        float* w   = (float*)d_ws;
        float* deg = w;                  // nal  (becomes dinv)
        float* a1  = w + nal;            // 16*nal (becomes g2)
        float* g1  = a1 + 16 * nal;      // 16*nal

        hipMemsetAsync(d_ws, 0, (nal * 17) * sizeof(float), stream);
        hipMemsetAsync(d_out, 0, (size_t)out_size * sizeof(float), stream);

        deg_kernel<<<(E + B - 1) / B, B, 0, stream>>>(dst, deg, E);
        dinv_kernel<<<(n + B - 1) / B, B, 0, stream>>>(deg, n);
        xform1_kernel<<<(n + B - 1) / B, B, 0, stream>>>(x, W1, deg, g1, n);
        long long total = (long long)E * HID;
        agg_kernel<<<(int)((total + B - 1) / B), B, 0, stream>>>(src, dst, g1, a1, total);
        fin1_xform2_nolds_kernel<<<(n + B - 1) / B, B, 0, stream>>>(a1, g1, deg, b1, W2, n);
        agg_kernel<<<(int)((total + B - 1) / B), B, 0, stream>>>(src, dst, a1, out, total);
        fin2_kernel<<<(n + B - 1) / B, B, 0, stream>>>(out, a1, deg, b2, n);
    }
}